// Round 1
// baseline (122.399 us; speedup 1.0000x reference)
//
#include <hip/hip_runtime.h>
#include <hip/hip_bf16.h>

#define BATCH 16384
#define DIM   512
#define UNITS 1024
#define GAMMA 0.5f

typedef __bf16 v8bf __attribute__((ext_vector_type(8)));
typedef __bf16 v4bf __attribute__((ext_vector_type(4)));
typedef float  v4f  __attribute__((ext_vector_type(4)));

__device__ __forceinline__ void async_copy16(const void* g, void* l) {
    __builtin_amdgcn_global_load_lds(
        (const __attribute__((address_space(1))) void*)g,
        (__attribute__((address_space(3))) void*)l,
        16 /*bytes*/, 0 /*offset*/, 0 /*aux*/);
}

// Convert inputs fp32 -> bf16 (row-major [BATCH][DIM]) and compute x_sq per row.
__global__ void prep_a_kernel(const float* __restrict__ in,
                              __bf16* __restrict__ A,
                              float* __restrict__ xsq) {
    const int row = blockIdx.x;     // 16384
    const int t   = threadIdx.x;    // 128 threads, 4 floats each = 512
    float4 v = ((const float4*)(in + (size_t)row * DIM))[t];
    float s = v.x * v.x + v.y * v.y + v.z * v.z + v.w * v.w;
    v4bf b;
    b[0] = (__bf16)v.x; b[1] = (__bf16)v.y; b[2] = (__bf16)v.z; b[3] = (__bf16)v.w;
    ((v4bf*)A)[(size_t)row * (DIM / 4) + t] = b;
    // wave reduce (width 64), then combine 2 waves via LDS
    for (int off = 32; off; off >>= 1) s += __shfl_down(s, off, 64);
    __shared__ float red[2];
    if ((t & 63) == 0) red[t >> 6] = s;
    __syncthreads();
    if (t == 0) xsq[row] = red[0] + red[1];
}

// Transpose-convert mu [DIM][UNITS] fp32 -> Bt [UNITS][DIM] bf16, compute mu_sq per column.
__global__ void prep_b_kernel(const float* __restrict__ mu,
                              __bf16* __restrict__ Bt,
                              float* __restrict__ musq) {
    const int n = blockIdx.x;       // 1024
    const int t = threadIdx.x;      // 128
    float s = 0.f;
    for (int k = t; k < DIM; k += 128) {
        float v = mu[(size_t)k * UNITS + n];
        s += v * v;
        Bt[(size_t)n * DIM + k] = (__bf16)v;
    }
    for (int off = 32; off; off >>= 1) s += __shfl_down(s, off, 64);
    __shared__ float red[2];
    if ((t & 63) == 0) red[t >> 6] = s;
    __syncthreads();
    if (t == 0) musq[n] = red[0] + red[1];
}

// 128x128 tile GEMM (bf16 MFMA 16x16x32), BK=32, fused RBF epilogue.
// 4 waves/block, each wave owns a 64x64 sub-tile as 4x4 MFMA tiles.
__global__ __launch_bounds__(256)
void rbf_gemm_kernel(const __bf16* __restrict__ A,
                     const __bf16* __restrict__ Bt,
                     const float* __restrict__ xsq,
                     const float* __restrict__ musq,
                     float* __restrict__ out) {
    __shared__ __attribute__((aligned(16))) __bf16 As[128 * 32];
    __shared__ __attribute__((aligned(16))) __bf16 Bs[128 * 32];

    const int t    = threadIdx.x;
    const int lane = t & 63;
    const int wave = t >> 6;
    const int quad = lane >> 4;     // 0..3
    const int lr   = lane & 15;     // 0..15
    const int wm   = (wave >> 1) * 64;
    const int wn   = (wave & 1) * 64;
    const int m0   = blockIdx.x * 128;
    const int n0   = blockIdx.y * 128;

    v4f acc[4][4];
#pragma unroll
    for (int i = 0; i < 4; i++)
#pragma unroll
        for (int j = 0; j < 4; j++) acc[i][j] = (v4f)0.f;

    // Staging geometry: tile is 128 rows x 32 cols bf16, stored contiguously
    // (row stride 32 elems) so global_load_lds's lane-ordered writes line up.
    // Thread t covers flat elems [t*8, t*8+8) per issue; issue 1 adds 2048.
    const int fr = t >> 2;              // (t*8)/32 : row within issue
    const int fc = (t & 3) * 8;         // (t*8)%32 : col
    const __bf16* ga0 = A  + (size_t)(m0 + fr)      * DIM + fc;
    const __bf16* ga1 = A  + (size_t)(m0 + 64 + fr) * DIM + fc;
    const __bf16* gb0 = Bt + (size_t)(n0 + fr)      * DIM + fc;
    const __bf16* gb1 = Bt + (size_t)(n0 + 64 + fr) * DIM + fc;
    __bf16* la0 = As + wave * 512;
    __bf16* la1 = As + 2048 + wave * 512;
    __bf16* lb0 = Bs + wave * 512;
    __bf16* lb1 = Bs + 2048 + wave * 512;

    for (int kt = 0; kt < DIM / 32; kt++) {
        const int k0 = kt * 32;
        async_copy16(ga0 + k0, la0);
        async_copy16(ga1 + k0, la1);
        async_copy16(gb0 + k0, lb0);
        async_copy16(gb1 + k0, lb1);
        __syncthreads();

        v8bf af[4], bfr[4];
#pragma unroll
        for (int i = 0; i < 4; i++)
            af[i] = *(const v8bf*)(As + (wm + i * 16 + lr) * 32 + quad * 8);
#pragma unroll
        for (int j = 0; j < 4; j++)
            bfr[j] = *(const v8bf*)(Bs + (wn + j * 16 + lr) * 32 + quad * 8);
#pragma unroll
        for (int i = 0; i < 4; i++)
#pragma unroll
            for (int j = 0; j < 4; j++)
                acc[i][j] = __builtin_amdgcn_mfma_f32_16x16x32_bf16(
                    af[i], bfr[j], acc[i][j], 0, 0, 0);
        __syncthreads();
    }

    // Epilogue: out = exp(-gamma * (xsq[m] - 2*cross + musq[n]))
    float mq[4];
#pragma unroll
    for (int j = 0; j < 4; j++) mq[j] = musq[n0 + wn + j * 16 + lr];

#pragma unroll
    for (int i = 0; i < 4; i++) {
#pragma unroll
        for (int r = 0; r < 4; r++) {
            const int grow = m0 + wm + i * 16 + quad * 4 + r;
            const float xs = xsq[grow];
            float* orow = out + (size_t)grow * UNITS + n0 + wn + lr;
#pragma unroll
            for (int j = 0; j < 4; j++) {
                float l2 = xs - 2.0f * acc[i][j][r] + mq[j];
                orow[j * 16] = __expf(-GAMMA * l2);
            }
        }
    }
}

extern "C" void kernel_launch(void* const* d_in, const int* in_sizes, int n_in,
                              void* d_out, int out_size, void* d_ws, size_t ws_size,
                              hipStream_t stream) {
    const float* inputs = (const float*)d_in[0];   // [16384, 512]
    const float* mu     = (const float*)d_in[1];   // [512, 1024]
    float* out = (float*)d_out;                    // [16384, 1024]

    char* ws = (char*)d_ws;
    __bf16* A    = (__bf16*)ws;                                       // 16 MiB
    __bf16* Bt   = (__bf16*)(ws + (size_t)BATCH * DIM * 2);           // 1 MiB
    float*  xsq  = (float*)(ws + (size_t)BATCH * DIM * 2 + (size_t)UNITS * DIM * 2);
    float*  musq = xsq + BATCH;

    prep_a_kernel<<<BATCH, 128, 0, stream>>>(inputs, A, xsq);
    prep_b_kernel<<<UNITS, 128, 0, stream>>>(mu, Bt, musq);
    rbf_gemm_kernel<<<dim3(BATCH / 128, UNITS / 128), 256, 0, stream>>>(
        A, Bt, xsq, musq, out);
}

// Round 2
// 120.958 us; speedup vs baseline: 1.0119x; 1.0119x over previous
//
#include <hip/hip_runtime.h>
#include <hip/hip_bf16.h>

#define BATCH 16384
#define DIM   512
#define UNITS 1024
#define GAMMA 0.5f

typedef __bf16 v8bf __attribute__((ext_vector_type(8)));
typedef float  v4f  __attribute__((ext_vector_type(4)));

__device__ __forceinline__ void async_copy16(const void* g, void* l) {
    __builtin_amdgcn_global_load_lds(
        (const __attribute__((address_space(1))) void*)g,
        (__attribute__((address_space(3))) void*)l,
        16 /*bytes*/, 0 /*offset*/, 0 /*aux*/);
}

// fp32 -> bf16 convert of inputs + per-row ||x||^2. One wave per row.
__global__ __launch_bounds__(256)
void prep_a_kernel(const float* __restrict__ in,
                   __bf16* __restrict__ A,
                   float* __restrict__ xsq) {
    const int t    = threadIdx.x;
    const int lane = t & 63;
    const int row  = blockIdx.x * 4 + (t >> 6);
    const float4* src = (const float4*)(in + (size_t)row * DIM);
    float4 a = src[lane * 2];
    float4 b = src[lane * 2 + 1];
    float s = a.x * a.x + a.y * a.y + a.z * a.z + a.w * a.w
            + b.x * b.x + b.y * b.y + b.z * b.z + b.w * b.w;
    v8bf o;
    o[0] = (__bf16)a.x; o[1] = (__bf16)a.y; o[2] = (__bf16)a.z; o[3] = (__bf16)a.w;
    o[4] = (__bf16)b.x; o[5] = (__bf16)b.y; o[6] = (__bf16)b.z; o[7] = (__bf16)b.w;
    *(v8bf*)(A + (size_t)row * DIM + lane * 8) = o;
    for (int off = 32; off; off >>= 1) s += __shfl_down(s, off, 64);
    if (lane == 0) xsq[row] = s;
}

// mu [DIM][UNITS] fp32 -> Bt [UNITS][DIM] bf16 via LDS transpose + col ||mu||^2.
// One block per 64-column tile; coalesced loads, vectorized bf16 stores.
__global__ __launch_bounds__(256)
void prep_b_kernel(const float* __restrict__ mu,
                   __bf16* __restrict__ Bt,
                   float* __restrict__ musq) {
    __shared__ float lds[64][65];
    __shared__ float red[64][4];
    const int t  = threadIdx.x;        // 256
    const int n0 = blockIdx.x * 64;
    const int c  = t & 63;             // load-phase column (n)
    const int r4 = t >> 6;             // load-phase row offset 0..3
    const int nl = t >> 2;             // write-phase row (n within tile)
    const int ks = (t & 3) * 16;       // write-phase k start
    float s = 0.f;
    for (int kc = 0; kc < DIM; kc += 64) {
        __syncthreads();
#pragma unroll
        for (int i = 0; i < 16; i++) {
            const int k = r4 + i * 4;
            lds[k][c] = mu[(size_t)(kc + k) * UNITS + n0 + c];
        }
        __syncthreads();
        v8bf o0, o1;
#pragma unroll
        for (int j = 0; j < 8; j++) {
            float v = lds[ks + j][nl];
            s += v * v;
            o0[j] = (__bf16)v;
        }
#pragma unroll
        for (int j = 0; j < 8; j++) {
            float v = lds[ks + 8 + j][nl];
            s += v * v;
            o1[j] = (__bf16)v;
        }
        *(v8bf*)(Bt + (size_t)(n0 + nl) * DIM + kc + ks) = o0;
        *(v8bf*)(Bt + (size_t)(n0 + nl) * DIM + kc + ks + 8) = o1;
    }
    red[nl][t & 3] = s;
    __syncthreads();
    if (t < 64) musq[n0 + t] = red[t][0] + red[t][1] + red[t][2] + red[t][3];
}

// 128x128 tile GEMM, BK=64, XOR-swizzled LDS, bf16 MFMA 16x16x32, fused RBF
// epilogue. 4 waves/block, each wave a 64x64 sub-tile (4x4 MFMA tiles).
// LDS layout: tile[r][g*8..g*8+7] stored at elem r*64 + (g ^ (r&7))*8 — the
// swizzle is realized on the WRITE side by permuting each lane's global chunk
// (global_load_lds is lane-linear in LDS), and on the READ side in the frag
// address. Kills the 8/16-way ds_read_b128 bank conflicts of the strided
// layout (start banks cover all eight 16B slots per 8 lanes -> 2-way = free).
__global__ __launch_bounds__(256)
void rbf_gemm_kernel(const __bf16* __restrict__ A,
                     const __bf16* __restrict__ Bt,
                     const float* __restrict__ xsq,
                     const float* __restrict__ musq,
                     float* __restrict__ out) {
    __shared__ __attribute__((aligned(16))) __bf16 As[128 * 64];
    __shared__ __attribute__((aligned(16))) __bf16 Bs[128 * 64];

    const int t    = threadIdx.x;
    const int lane = t & 63;
    const int wave = t >> 6;
    const int quad = lane >> 4;
    const int lr   = lane & 15;
    const int wm   = (wave >> 1) * 64;
    const int wn   = (wave & 1) * 64;
    const int m0   = blockIdx.x * 128;
    const int n0   = blockIdx.y * 128;

    v4f acc[4][4];
#pragma unroll
    for (int i = 0; i < 4; i++)
#pragma unroll
        for (int j = 0; j < 4; j++) acc[i][j] = (v4f)0.f;

    // Staging: per issue `it`, thread t covers row fr = it*32 + (t>>3),
    // stored group t&7, which holds logical group (t&7) ^ (fr&7).
    const int fr_base = t >> 3;                       // row within issue
    const int swz     = (t & 7) ^ (fr_base & 7);      // logical group fetched
    const __bf16* ga[4];
    const __bf16* gb[4];
#pragma unroll
    for (int it = 0; it < 4; it++) {
        ga[it] = A  + (size_t)(m0 + it * 32 + fr_base) * DIM + swz * 8;
        gb[it] = Bt + (size_t)(n0 + it * 32 + fr_base) * DIM + swz * 8;
    }
    __bf16* la[4];
    __bf16* lb[4];
#pragma unroll
    for (int it = 0; it < 4; it++) {
        la[it] = As + it * 2048 + wave * 512;
        lb[it] = Bs + it * 2048 + wave * 512;
    }

    // Fragment read swizzle: row r = wm|wn + i*16 + lr, logical group
    // g = kh*4 + quad  ->  stored group (kh*4 + quad) ^ (lr&7).
    const int sL = quad ^ (lr & 7);
    const int arow = (wm + lr) * 64;
    const int brow = (wn + lr) * 64;

    for (int kt = 0; kt < DIM / 64; kt++) {
        const int k0 = kt * 64;
#pragma unroll
        for (int it = 0; it < 4; it++) {
            async_copy16(ga[it] + k0, la[it]);
            async_copy16(gb[it] + k0, lb[it]);
        }
        __syncthreads();

#pragma unroll
        for (int kh = 0; kh < 2; kh++) {
            const int so = (sL ^ (kh << 2)) * 8;
            v8bf af[4], bfr[4];
#pragma unroll
            for (int i = 0; i < 4; i++)
                af[i] = *(const v8bf*)(As + arow + i * 1024 + so);
#pragma unroll
            for (int j = 0; j < 4; j++)
                bfr[j] = *(const v8bf*)(Bs + brow + j * 1024 + so);
#pragma unroll
            for (int i = 0; i < 4; i++)
#pragma unroll
                for (int j = 0; j < 4; j++)
                    acc[i][j] = __builtin_amdgcn_mfma_f32_16x16x32_bf16(
                        af[i], bfr[j], acc[i][j], 0, 0, 0);
        }
        __syncthreads();
    }

    // Epilogue: out = exp(-gamma * (xsq[m] - 2*cross + musq[n]))
    float mq[4];
#pragma unroll
    for (int j = 0; j < 4; j++) mq[j] = musq[n0 + wn + j * 16 + lr];

#pragma unroll
    for (int i = 0; i < 4; i++) {
#pragma unroll
        for (int r = 0; r < 4; r++) {
            const int grow = m0 + wm + i * 16 + quad * 4 + r;
            const float xs = xsq[grow];
            float* orow = out + (size_t)grow * UNITS + n0 + wn + lr;
#pragma unroll
            for (int j = 0; j < 4; j++) {
                float l2 = xs - 2.0f * acc[i][j][r] + mq[j];
                orow[j * 16] = __expf(-GAMMA * l2);
            }
        }
    }
}

extern "C" void kernel_launch(void* const* d_in, const int* in_sizes, int n_in,
                              void* d_out, int out_size, void* d_ws, size_t ws_size,
                              hipStream_t stream) {
    const float* inputs = (const float*)d_in[0];   // [16384, 512] fp32
    const float* mu     = (const float*)d_in[1];   // [512, 1024] fp32
    float* out = (float*)d_out;                    // [16384, 1024] fp32

    char* ws = (char*)d_ws;
    __bf16* A    = (__bf16*)ws;                                       // 16 MiB
    __bf16* Bt   = (__bf16*)(ws + (size_t)BATCH * DIM * 2);           // 1 MiB
    float*  xsq  = (float*)(ws + (size_t)BATCH * DIM * 2 + (size_t)UNITS * DIM * 2);
    float*  musq = xsq + BATCH;

    prep_a_kernel<<<BATCH / 4, 256, 0, stream>>>(inputs, A, xsq);
    prep_b_kernel<<<UNITS / 64, 256, 0, stream>>>(mu, Bt, musq);
    rbf_gemm_kernel<<<dim3(BATCH / 128, UNITS / 128), 256, 0, stream>>>(
        A, Bt, xsq, musq, out);
}